// Round 11
// baseline (62.596 us; speedup 1.0000x reference)
//
#include <hip/hip_runtime.h>
#include <hip/hip_bf16.h>
#include <stdint.h>

typedef __attribute__((ext_vector_type(8))) short short8;
typedef __attribute__((ext_vector_type(4))) float f32x4;

constexpr int Tt = 8192, Kd = 1024, Nd = 1024, Gn = 8;
constexpr int BM = 128, BN = 128, BK = 32;
constexpr int NKT = Kd / BK; // 32 K-tiles

static __device__ __forceinline__ short f2bf(float x) {
    __hip_bfloat16 b = __float2bfloat16(x);
    return *reinterpret_cast<short*>(&b);
}

// raw barrier: own ds_writes drained; global loads stay in flight (NO vmcnt drain)
#define BAR() do { \
    asm volatile("s_waitcnt lgkmcnt(0)" ::: "memory"); \
    __builtin_amdgcn_s_barrier(); \
    __builtin_amdgcn_sched_barrier(0); \
} while (0)

// B reg-prefetch: 16 strided floats (W[k][n], k-major stride Nd)
#define LOAD_B(dst, kt) do { \
    const float* p = Wg + (size_t)((kt) * BK + kh * 16) * Nd + col0 + rr; \
    _Pragma("unroll") for (int j = 0; j < 16; ++j) dst[j] = p[(size_t)j * Nd]; \
} while (0)

// cvt + 2 swizzled ds_write_b128 (row rr, granules 2kh, 2kh+1, slot g^xr)
#define WRITE_B(src, buf) do { \
    short8 v0, v1; \
    _Pragma("unroll") for (int j = 0; j < 8; ++j) { v0[j] = f2bf(src[j]); v1[j] = f2bf(src[8 + j]); } \
    *(short8*)&Bs[buf][rr * 32 + (((kh * 2) ^ xr) << 3)] = v0; \
    *(short8*)&Bs[buf][rr * 32 + (((kh * 2 + 1) ^ xr) << 3)] = v1; \
} while (0)

__global__ __launch_bounds__(256, 2)
void gemm_fused(const float* __restrict__ H, const float* __restrict__ W,
                const int* __restrict__ counts, float* __restrict__ out)
{
    // bf16 LDS tiles, 64B rows (32 shorts = 4 granules of 16B), dbuf, 32KB total.
    // slot(row, g) = g ^ ((row ^ (row>>2)) & 3)  -> <=2-way (free) on b128 r/w.
    __shared__ __align__(16) short As[2][BM * BK];
    __shared__ __align__(16) short Bs[2][BN * BK];

    const int tid = threadIdx.x;
    const int bid = blockIdx.x;
    const int wg = (bid & 7) * 64 + (bid >> 3);   // bijective XCD swizzle (512%8==0)
    const int mt = wg >> 3, nt = wg & 7;
    const int row0 = mt * BM, col0 = nt * BN;

    int g = 0;
    { int c = 0; for (int i = 0; i < Gn; ++i) { c += counts[i]; if (row0 >= c) g = i + 1; } }
    const float* __restrict__ Wg = W + (size_t)g * Kd * Nd;

    const int wid = tid >> 6, lane = tid & 63;
    const int wm = wid >> 1, wn = wid & 1;        // 2x2 waves, 64x64 each
    const int l15 = lane & 15, l4 = lane >> 4;
    const int xl = (l15 ^ (l15 >> 2)) & 3;        // read-side swizzle (row bits 0..3)

    const int rr = tid >> 1;                      // staging row (A) / col (B): 0..127
    const int kh = tid & 1;                       // k-half (16 elems)
    const int xr = (rr ^ (rr >> 2)) & 3;          // write-side swizzle

    f32x4 acc[4][4];
#pragma unroll
    for (int i = 0; i < 4; ++i)
#pragma unroll
        for (int j = 0; j < 4; ++j) acc[i][j] = (f32x4)0.0f;

    f32x4 av[4];            // A depth-1: 16 consecutive floats
    float bv0[16], bv1[16]; // B depth-2: two NAMED sets (B(t) -> bv[t&1])

    auto load_a = [&](int kt) {
        const float* p = H + (size_t)(row0 + rr) * Kd + kt * BK + kh * 16;
#pragma unroll
        for (int j = 0; j < 4; ++j) av[j] = *(const f32x4*)(p + j * 4);
    };
    auto write_a = [&](int buf) {
        short8 v0, v1;
#pragma unroll
        for (int j = 0; j < 4; ++j) { v0[j] = f2bf(av[0][j]); v0[4 + j] = f2bf(av[1][j]);
                                      v1[j] = f2bf(av[2][j]); v1[4 + j] = f2bf(av[3][j]); }
        *(short8*)&As[buf][rr * 32 + (((kh * 2) ^ xr) << 3)] = v0;
        *(short8*)&As[buf][rr * 32 + (((kh * 2 + 1) ^ xr) << 3)] = v1;
    };

    auto compute = [&](int buf) {
        short8 af[4], bf[4];
#pragma unroll
        for (int mi = 0; mi < 4; ++mi) {
            const int m = wm * 64 + mi * 16 + l15;
            af[mi] = *(const short8*)&As[buf][m * 32 + ((l4 ^ xl) << 3)];
        }
#pragma unroll
        for (int ni = 0; ni < 4; ++ni) {
            const int n = wn * 64 + ni * 16 + l15;
            bf[ni] = *(const short8*)&Bs[buf][n * 32 + ((l4 ^ xl) << 3)];
        }
#pragma unroll
        for (int mi = 0; mi < 4; ++mi)
#pragma unroll
            for (int ni = 0; ni < 4; ++ni)
                acc[mi][ni] = __builtin_amdgcn_mfma_f32_16x16x32_bf16(
                    af[mi], bf[ni], acc[mi][ni], 0, 0, 0);
    };

    // prologue: tile0 staged (latency exposed once); B1 -> bv1 in flight across barrier
    LOAD_B(bv0, 0);
    load_a(0);
    WRITE_B(bv0, 0);
    write_a(0);
    LOAD_B(bv1, 1);
    BAR();

    // main loop, unrolled x2 for static reg-set selection (rule #20).
    // Phase kt: prefetch A(kt+1) [cover=compute] and B(kt+2) [cover=full phase];
    // compute(kt); stage tile kt+1 (B from 1-phase-old set); raw barrier, no vmcnt drain.
    for (int kt2 = 0; kt2 < NKT; kt2 += 2) {
        // even phase: compute buf0, stage -> buf1, B prefetch -> bv0
        if (kt2 + 1 < NKT) load_a(kt2 + 1);
        if (kt2 + 2 < NKT) LOAD_B(bv0, kt2 + 2);
        compute(0);
        if (kt2 + 1 < NKT) { WRITE_B(bv1, 1); write_a(1); }
        BAR();
        // odd phase: compute buf1, stage -> buf0, B prefetch -> bv1
        if (kt2 + 2 < NKT) load_a(kt2 + 2);
        if (kt2 + 3 < NKT) LOAD_B(bv1, kt2 + 3);
        compute(1);
        if (kt2 + 2 < NKT) { WRITE_B(bv0, 0); write_a(0); }
        BAR();
    }

    // epilogue: C/D layout col=lane&15, row=(lane>>4)*4+reg (m89-verified)
#pragma unroll
    for (int mi = 0; mi < 4; ++mi) {
        const int rbase = row0 + wm * 64 + mi * 16 + l4 * 4;
#pragma unroll
        for (int ni = 0; ni < 4; ++ni) {
            const int c = col0 + wn * 64 + ni * 16 + l15;
#pragma unroll
            for (int r = 0; r < 4; ++r)
                out[(size_t)(rbase + r) * Nd + c] = acc[mi][ni][r];
        }
    }
}

extern "C" void kernel_launch(void* const* d_in, const int* in_sizes, int n_in,
                              void* d_out, int out_size, void* d_ws, size_t ws_size,
                              hipStream_t stream) {
    const float* H = (const float*)d_in[0];
    const float* W = (const float*)d_in[1];
    const int* counts = (const int*)d_in[2];
    float* out = (float*)d_out;
    const int grid = (Tt / BM) * (Nd / BN);  // 64 * 8 = 512 blocks
    gemm_fused<<<grid, 256, 0, stream>>>(H, W, counts, out);
}